// Round 1
// baseline (7997.469 us; speedup 1.0000x reference)
//
#include <hip/hip_runtime.h>
#include <hip/hip_bf16.h>
#include <cstdint>
#include <cstddef>

// AxialAttentionModule: row-MHA (S=512, batch 128, masked) + col-MHA (S=32,
// batch 2048) + residual + LayerNorm.  Round 1: correctness-first fp32
// pipeline, bf16 intermediates (QKV 100MB, attn-out 33MB, fp32 acc 67MB
// => ~192 MiB of d_ws).
//
// Fixed shapes (hardcoded): N=512 D=32 B=4 E=256 H=4 HD=64.

typedef __hip_bfloat16 bf16;

#define NN 512
#define DD 32
#define BB 4
#define EE 256
#define HH 4
#define HDIM 64
#define DB (DD*BB)        // 128  (row-attn batch)
#define MTOK (NN*DD*BB)   // 65536 tokens
#define QKV3 (3*EE)       // 768

__device__ __forceinline__ float bf2f(bf16 x){ return __bfloat162float(x); }
__device__ __forceinline__ bf16 f2bf(float x){ return __float2bfloat16(x); }

// ---------------------------------------------------------------------------
// Generic tiled GEMM: C[M,Nout] = A[M,256] @ W[Nout,256]^T + bias
// AMODE: 0 = A fp32 direct (m,k)    (src as row-tokens / contiguous)
//        1 = A fp32 col-permuted    (src viewed as col-tokens (d,n,b))
//        2 = A bf16 direct          (attention outputs)
// CMODE: 0 = write bf16 direct      (QKV buffers)
//        1 = write fp32 direct SET  (row out-proj -> acc)
//        2 = fp32 ADD at col-perm   (col out-proj -> acc at (n,d,b))
// Tile 64x64, BK=32, 256 threads, 4x4 per thread.
// ---------------------------------------------------------------------------
template<int AMODE, int CMODE>
__global__ __launch_bounds__(256) void gemm_kernel(
    const void* __restrict__ Av, const float* __restrict__ W,
    const float* __restrict__ bias, void* __restrict__ Cv, int Nout)
{
  const int K = EE;
  __shared__ float As[64][33];
  __shared__ float Bs[32][65];
  int bm = blockIdx.y, bn = blockIdx.x;
  int tid = threadIdx.x;
  int tx = tid & 15, ty = tid >> 4;
  float c[4][4] = {};
  for (int k0 = 0; k0 < K; k0 += 32) {
    for (int i = tid; i < 64*32; i += 256) {
      int r = i >> 5, cc = i & 31;
      int m = bm*64 + r;
      int k = k0 + cc;
      float v;
      if (AMODE == 0) {
        v = ((const float*)Av)[(size_t)m*K + k];
      } else if (AMODE == 1) {
        int d = m >> 11, rem = m & 2047, n = rem >> 2, b = rem & 3;
        v = ((const float*)Av)[(((size_t)n*DD + d)*BB + b)*EE + k];
      } else {
        v = bf2f(((const bf16*)Av)[(size_t)m*K + k]);
      }
      As[r][cc] = v;
    }
    for (int i = tid; i < 32*64; i += 256) {
      int kk = i & 31, n = i >> 5;
      Bs[kk][n] = W[(size_t)(bn*64 + n)*K + k0 + kk];
    }
    __syncthreads();
    #pragma unroll
    for (int kk = 0; kk < 32; ++kk) {
      float a[4], b[4];
      #pragma unroll
      for (int i = 0; i < 4; ++i) a[i] = As[ty*4+i][kk];
      #pragma unroll
      for (int j = 0; j < 4; ++j) b[j] = Bs[kk][tx*4+j];
      #pragma unroll
      for (int i = 0; i < 4; ++i)
        #pragma unroll
        for (int j = 0; j < 4; ++j) c[i][j] += a[i]*b[j];
    }
    __syncthreads();
  }
  #pragma unroll
  for (int i = 0; i < 4; ++i) {
    int m = bm*64 + ty*4 + i;
    #pragma unroll
    for (int j = 0; j < 4; ++j) {
      int n = bn*64 + tx*4 + j;
      float val = c[i][j] + bias[n];
      if (CMODE == 0) {
        ((bf16*)Cv)[(size_t)m*Nout + n] = f2bf(val);
      } else if (CMODE == 1) {
        ((float*)Cv)[(size_t)m*Nout + n] = val;
      } else {
        int d = m >> 11, rem = m & 2047, n2 = rem >> 2, b = rem & 3;
        ((float*)Cv)[(((size_t)n2*DD + d)*BB + b)*EE + n] += val;
      }
    }
  }
}

// ---------------------------------------------------------------------------
// Row attention: one block per (t, h, q).  S=512 keys, mask: queries q>=sep
// may only attend keys k<sep.  qkv layout: token (n,t) at (n*DB+t)*768,
// Q at +0, K at +256, V at +512, head slice h*64.
// ---------------------------------------------------------------------------
__global__ __launch_bounds__(256) void attn_row_kernel(
    const bf16* __restrict__ qkv, bf16* __restrict__ attn,
    const int* __restrict__ sep_ptr)
{
  int bid = blockIdx.x;           // bid = (t*4 + h)*512 + q
  int t = bid >> 11;
  int h = (bid >> 9) & 3;
  int q = bid & 511;
  int tid = threadIdx.x;
  int sep = *sep_ptr;
  int kmax = (q >= sep) ? sep : NN;

  __shared__ float qs[HDIM];
  __shared__ float sc[NN];
  __shared__ float red[256];

  if (tid < HDIM)
    qs[tid] = 0.125f * bf2f(qkv[((size_t)q*DB + t)*QKV3 + h*HDIM + tid]);
  __syncthreads();

  for (int k = tid; k < NN; k += 256) {
    float s = -1e30f;
    if (k < kmax) {
      const bf16* Kp = qkv + ((size_t)k*DB + t)*QKV3 + EE + h*HDIM;
      float acc = 0.f;
      #pragma unroll
      for (int d = 0; d < HDIM; ++d) acc += qs[d]*bf2f(Kp[d]);
      s = acc;
    }
    sc[k] = s;
  }
  __syncthreads();

  // max
  red[tid] = fmaxf(sc[tid], sc[tid+256]);
  __syncthreads();
  for (int s2 = 128; s2 > 0; s2 >>= 1) {
    if (tid < s2) red[tid] = fmaxf(red[tid], red[tid+s2]);
    __syncthreads();
  }
  float mx = red[0];
  __syncthreads();

  // exp + sum
  float lsum = 0.f;
  for (int k = tid; k < NN; k += 256) {
    float p = (k < kmax) ? __expf(sc[k] - mx) : 0.f;
    sc[k] = p;
    lsum += p;
  }
  red[tid] = lsum;
  __syncthreads();
  for (int s2 = 128; s2 > 0; s2 >>= 1) {
    if (tid < s2) red[tid] += red[tid+s2];
    __syncthreads();
  }
  float inv = 1.f / red[0];
  __syncthreads();

  // PV: 64 outputs x 4 k-partials
  int e = tid & 63, part = tid >> 6;
  float acc = 0.f;
  for (int k = part*128; k < part*128 + 128; ++k) {
    acc += sc[k] * bf2f(qkv[((size_t)k*DB + t)*QKV3 + 2*EE + h*HDIM + e]);
  }
  red[tid] = acc;
  __syncthreads();
  if (part == 0) {
    float o = (red[e] + red[64+e] + red[128+e] + red[192+e]) * inv;
    attn[((size_t)q*DB + t)*EE + h*HDIM + e] = f2bf(o);
  }
}

// ---------------------------------------------------------------------------
// Col attention: one block per (n, b, h).  S=32 over the D axis, no mask.
// qkv (col layout): token (d,n,b) at ((d*NN+n)*BB+b)*768.
// ---------------------------------------------------------------------------
__global__ __launch_bounds__(256) void attn_col_kernel(
    const bf16* __restrict__ qkv, bf16* __restrict__ attn)
{
  int bid = blockIdx.x;           // bid = (n*4 + b)*4 + h
  int n = bid >> 4;
  int b = (bid >> 2) & 3;
  int h = bid & 3;
  int tid = threadIdx.x;

  __shared__ float Qs[DD][HDIM], Ks[DD][HDIM], Vs[DD][HDIM];
  __shared__ float P[DD][DD+1];

  for (int i = tid; i < DD*HDIM; i += 256) {
    int dq = i >> 6, e = i & 63;
    size_t base = (((size_t)dq*NN + n)*BB + b)*QKV3 + h*HDIM + e;
    Qs[dq][e] = bf2f(qkv[base]);
    Ks[dq][e] = bf2f(qkv[base + EE]);
    Vs[dq][e] = bf2f(qkv[base + 2*EE]);
  }
  __syncthreads();

  for (int i = tid; i < DD*DD; i += 256) {
    int qi = i >> 5, ki = i & 31;
    float s = 0.f;
    #pragma unroll
    for (int e = 0; e < HDIM; ++e) s += Qs[qi][e]*Ks[ki][e];
    P[qi][ki] = s * 0.125f;
  }
  __syncthreads();

  if (tid < DD) {
    float mx = -1e30f;
    for (int ki = 0; ki < DD; ++ki) mx = fmaxf(mx, P[tid][ki]);
    float sum = 0.f;
    for (int ki = 0; ki < DD; ++ki) {
      float p = __expf(P[tid][ki] - mx);
      P[tid][ki] = p;
      sum += p;
    }
    float invs = 1.f / sum;
    for (int ki = 0; ki < DD; ++ki) P[tid][ki] *= invs;
  }
  __syncthreads();

  for (int i = tid; i < DD*HDIM; i += 256) {
    int qi = i >> 6, e = i & 63;
    float acc = 0.f;
    #pragma unroll
    for (int ki = 0; ki < DD; ++ki) acc += P[qi][ki]*Vs[ki][e];
    attn[(((size_t)qi*NN + n)*BB + b)*EE + h*HDIM + e] = f2bf(acc);
  }
}

// ---------------------------------------------------------------------------
// Final: out = LayerNorm(src + acc) with gamma/beta.  One block per token.
// ---------------------------------------------------------------------------
__global__ __launch_bounds__(256) void ln_kernel(
    const float* __restrict__ src, const float* __restrict__ acc,
    const float* __restrict__ g, const float* __restrict__ b,
    float* __restrict__ out)
{
  int m = blockIdx.x;
  int e = threadIdx.x;
  __shared__ float red[256];
  size_t idx = (size_t)m*EE + e;
  float x = src[idx] + acc[idx];
  red[e] = x;
  __syncthreads();
  for (int s2 = 128; s2 > 0; s2 >>= 1) {
    if (e < s2) red[e] += red[e+s2];
    __syncthreads();
  }
  float mu = red[0] * (1.f/EE);
  __syncthreads();
  float xm = x - mu;
  red[e] = xm*xm;
  __syncthreads();
  for (int s2 = 128; s2 > 0; s2 >>= 1) {
    if (e < s2) red[e] += red[e+s2];
    __syncthreads();
  }
  float var = red[0] * (1.f/EE);
  out[idx] = xm * rsqrtf(var + 1e-5f) * g[e] + b[e];
}

// ---------------------------------------------------------------------------
extern "C" void kernel_launch(void* const* d_in, const int* in_sizes, int n_in,
                              void* d_out, int out_size, void* d_ws, size_t ws_size,
                              hipStream_t stream)
{
  const float* src      = (const float*)d_in[0];
  const float* w_in_row = (const float*)d_in[1];
  const float* b_in_row = (const float*)d_in[2];
  const float* w_out_row= (const float*)d_in[3];
  const float* b_out_row= (const float*)d_in[4];
  const float* w_in_col = (const float*)d_in[5];
  const float* b_in_col = (const float*)d_in[6];
  const float* w_out_col= (const float*)d_in[7];
  const float* b_out_col= (const float*)d_in[8];
  const float* ln_g     = (const float*)d_in[9];
  const float* ln_b     = (const float*)d_in[10];
  const int*   sep_ptr  = (const int*)d_in[12];
  float* out = (float*)d_out;

  char* ws = (char*)d_ws;
  bf16*  qkv  = (bf16*)(ws);                      // 65536*768*2  = 100663296 B
  bf16*  attn = (bf16*)(ws + 100663296);          // 65536*256*2  =  33554432 B
  float* acc  = (float*)(ws + 134217728);         // 65536*256*4  =  67108864 B

  dim3 blk(256);

  // 1. row QKV:  (65536,256) @ (768,256)^T -> qkv bf16
  gemm_kernel<0,0><<<dim3(QKV3/64, MTOK/64), blk, 0, stream>>>(
      src, w_in_row, b_in_row, qkv, QKV3);
  // 2. row attention (masked)
  attn_row_kernel<<<dim3(DB*HH*NN), blk, 0, stream>>>(qkv, attn, sep_ptr);
  // 3. row out-proj -> acc (SET)
  gemm_kernel<2,1><<<dim3(EE/64, MTOK/64), blk, 0, stream>>>(
      attn, w_out_row, b_out_row, acc, EE);
  // 4. col QKV (A loads permuted to col-token order)
  gemm_kernel<1,0><<<dim3(QKV3/64, MTOK/64), blk, 0, stream>>>(
      src, w_in_col, b_in_col, qkv, QKV3);
  // 5. col attention
  attn_col_kernel<<<dim3(NN*BB*HH), blk, 0, stream>>>(qkv, attn);
  // 6. col out-proj -> acc (ADD at permuted (n,d,b) index)
  gemm_kernel<2,2><<<dim3(EE/64, MTOK/64), blk, 0, stream>>>(
      attn, w_out_col, b_out_col, acc, EE);
  // 7. residual + LayerNorm
  ln_kernel<<<dim3(MTOK), blk, 0, stream>>>(src, acc, ln_g, ln_b, out);
}

// Round 2
// 1694.647 us; speedup vs baseline: 4.7193x; 4.7193x over previous
//
#include <hip/hip_runtime.h>
#include <hip/hip_bf16.h>
#include <cstdint>
#include <cstddef>

// AxialAttentionModule round 2: row attention rewritten as MFMA flash-style
// kernel (was 6.46 ms scalar, 81% of runtime). GEMMs still fp32 VALU (next).
//
// Fixed shapes: N=512 D=32 B=4 E=256 H=4 HD=64.

typedef __hip_bfloat16 bf16;
typedef __attribute__((ext_vector_type(8))) short bf16x8;
typedef __attribute__((ext_vector_type(4))) float f32x4;

#define NN 512
#define DD 32
#define BB 4
#define EE 256
#define HH 4
#define HDIM 64
#define DB (DD*BB)        // 128
#define MTOK (NN*DD*BB)   // 65536
#define QKV3 (3*EE)       // 768
#define QBLK 64
#define KBLK 64

__device__ __forceinline__ float bf2f(bf16 x){ return __bfloat162float(x); }
__device__ __forceinline__ bf16 f2bf(float x){ return __float2bfloat16(x); }

// ---------------------------------------------------------------------------
// Generic tiled GEMM: C[M,Nout] = A[M,256] @ W[Nout,256]^T + bias
// (unchanged from round 1 — fp32 VALU, to be MFMA'd next round)
// ---------------------------------------------------------------------------
template<int AMODE, int CMODE>
__global__ __launch_bounds__(256) void gemm_kernel(
    const void* __restrict__ Av, const float* __restrict__ W,
    const float* __restrict__ bias, void* __restrict__ Cv, int Nout)
{
  const int K = EE;
  __shared__ float As[64][33];
  __shared__ float Bs[32][65];
  int bm = blockIdx.y, bn = blockIdx.x;
  int tid = threadIdx.x;
  int tx = tid & 15, ty = tid >> 4;
  float c[4][4] = {};
  for (int k0 = 0; k0 < K; k0 += 32) {
    for (int i = tid; i < 64*32; i += 256) {
      int r = i >> 5, cc = i & 31;
      int m = bm*64 + r;
      int k = k0 + cc;
      float v;
      if (AMODE == 0) {
        v = ((const float*)Av)[(size_t)m*K + k];
      } else if (AMODE == 1) {
        int d = m >> 11, rem = m & 2047, n = rem >> 2, b = rem & 3;
        v = ((const float*)Av)[(((size_t)n*DD + d)*BB + b)*EE + k];
      } else {
        v = bf2f(((const bf16*)Av)[(size_t)m*K + k]);
      }
      As[r][cc] = v;
    }
    for (int i = tid; i < 32*64; i += 256) {
      int kk = i & 31, n = i >> 5;
      Bs[kk][n] = W[(size_t)(bn*64 + n)*K + k0 + kk];
    }
    __syncthreads();
    #pragma unroll
    for (int kk = 0; kk < 32; ++kk) {
      float a[4], b[4];
      #pragma unroll
      for (int i = 0; i < 4; ++i) a[i] = As[ty*4+i][kk];
      #pragma unroll
      for (int j = 0; j < 4; ++j) b[j] = Bs[kk][tx*4+j];
      #pragma unroll
      for (int i = 0; i < 4; ++i)
        #pragma unroll
        for (int j = 0; j < 4; ++j) c[i][j] += a[i]*b[j];
    }
    __syncthreads();
  }
  #pragma unroll
  for (int i = 0; i < 4; ++i) {
    int m = bm*64 + ty*4 + i;
    #pragma unroll
    for (int j = 0; j < 4; ++j) {
      int n = bn*64 + tx*4 + j;
      float val = c[i][j] + bias[n];
      if (CMODE == 0) {
        ((bf16*)Cv)[(size_t)m*Nout + n] = f2bf(val);
      } else if (CMODE == 1) {
        ((float*)Cv)[(size_t)m*Nout + n] = val;
      } else {
        int d = m >> 11, rem = m & 2047, n2 = rem >> 2, b = rem & 3;
        ((float*)Cv)[(((size_t)n2*DD + d)*BB + b)*EE + n] += val;
      }
    }
  }
}

// ---------------------------------------------------------------------------
// Row attention, MFMA flash-style.
// Grid: bid = (t*4 + h)*8 + qt  -> 128*4*8 = 4096 blocks, 256 thr (4 waves).
// Each wave owns 16 q rows (QBLK=64/block); K loop in tiles of KBLK=64.
// mfma_f32_16x16x32_bf16 layouts (m89-verified):
//   A: lane l holds A[l&15][(l>>4)*8 + j]      (8 contiguous bf16)
//   B: lane l holds B[(l>>4)*8 + j][l&15]      (= row l&15 of B^T, contiguous)
//   D: lane l holds D[(l>>4)*4 + r][l&15]
// ---------------------------------------------------------------------------
__global__ __launch_bounds__(256) void attn_row_mfma(
    const bf16* __restrict__ qkv, bf16* __restrict__ attn,
    const int* __restrict__ sep_ptr)
{
  const int bid = blockIdx.x;
  const int qt = bid & 7;
  const int h  = (bid >> 3) & 3;
  const int t  = bid >> 5;
  const int sep = *sep_ptr;

  const int tid  = threadIdx.x;
  const int wid  = tid >> 6;
  const int lane = tid & 63;
  const int lo = lane & 15, hi = lane >> 4;

  // +8 pad: row stride 144B (9x16) -> 16B-aligned b128, ~2-way banks (free)
  __shared__ bf16 Ks[KBLK][HDIM + 8];
  __shared__ bf16 Vt[HDIM][KBLK + 8];
  __shared__ bf16 Ps[4][16][KBLK + 8];

  const int qb = qt * QBLK;
  const int q0 = qb + wid * 16;

  // Q A-frags (row q0+lo), two k-chunks of 32 along d
  bf16x8 qf[2];
  {
    const bf16* Qp = qkv + ((size_t)(q0 + lo) * DB + t) * QKV3 + h * HDIM;
    qf[0] = *(const bf16x8*)(Qp + hi * 8);
    qf[1] = *(const bf16x8*)(Qp + 32 + hi * 8);
  }

  f32x4 Oa[4] = {{0,0,0,0},{0,0,0,0},{0,0,0,0},{0,0,0,0}};
  float m_run[4] = {-1e30f,-1e30f,-1e30f,-1e30f};
  float l_run[4] = {0.f,0.f,0.f,0.f};

  // all q rows in this block >= sep  =>  only keys < sep
  const int nkt = (qb >= sep) ? ((sep + KBLK - 1) >> 6) : (NN >> 6);

  for (int kt = 0; kt < nkt; ++kt) {
    const int k0 = kt * KBLK;
    __syncthreads();   // prev iteration's Ks/Vt reads done
    // ---- stage K (row-major) and V^T, cooperatively (256 thr) ----
    {
      const int r = tid >> 2;            // key row 0..63
      const int c = (tid & 3) * 16;      // d col base
      const bf16* Kp = qkv + ((size_t)(k0 + r) * DB + t) * QKV3 + EE + h * HDIM + c;
      bf16x8 kv0 = ((const bf16x8*)Kp)[0];
      bf16x8 kv1 = ((const bf16x8*)Kp)[1];
      *(bf16x8*)&Ks[r][c]     = kv0;
      *(bf16x8*)&Ks[r][c + 8] = kv1;
      const bf16* Vp = Kp + EE;
      bf16x8 vv0 = ((const bf16x8*)Vp)[0];
      bf16x8 vv1 = ((const bf16x8*)Vp)[1];
      #pragma unroll
      for (int j = 0; j < 8; ++j) {
        Vt[c + j][r]     = ((const bf16*)&vv0)[j];
        Vt[c + 8 + j][r] = ((const bf16*)&vv1)[j];
      }
    }
    __syncthreads();

    // ---- QK^T: 4 key-blocks of 16, each K=64 in 2 MFMA ----
    f32x4 sc[4];
    #pragma unroll
    for (int kb = 0; kb < 4; ++kb) {
      f32x4 acc = {0,0,0,0};
      #pragma unroll
      for (int kc = 0; kc < 2; ++kc) {
        bf16x8 kf = *(const bf16x8*)&Ks[kb*16 + lo][kc*32 + hi*8];
        acc = __builtin_amdgcn_mfma_f32_16x16x32_bf16(qf[kc], kf, acc, 0, 0, 0);
      }
      sc[kb] = acc;
    }

    // ---- scale + mask + online softmax ----
    float tmax[4] = {-1e30f,-1e30f,-1e30f,-1e30f};
    #pragma unroll
    for (int kb = 0; kb < 4; ++kb) {
      const int kk = k0 + kb*16 + lo;
      #pragma unroll
      for (int r = 0; r < 4; ++r) {
        float sv = sc[kb][r] * 0.125f;
        const int qq = q0 + hi*4 + r;
        if (qq >= sep && kk >= sep) sv = -1e30f;
        sc[kb][r] = sv;
        tmax[r] = fmaxf(tmax[r], sv);
      }
    }
    #pragma unroll
    for (int r = 0; r < 4; ++r) {
      #pragma unroll
      for (int off = 1; off < 16; off <<= 1)
        tmax[r] = fmaxf(tmax[r], __shfl_xor(tmax[r], off));
    }
    float psum[4];
    #pragma unroll
    for (int r = 0; r < 4; ++r) {
      const float mn = fmaxf(m_run[r], tmax[r]);
      const float corr = __expf(m_run[r] - mn);
      m_run[r] = mn;
      float s0 = 0.f;
      #pragma unroll
      for (int kb = 0; kb < 4; ++kb) {
        const float p = __expf(sc[kb][r] - mn);
        sc[kb][r] = p;
        s0 += p;
      }
      psum[r] = s0;
      l_run[r] *= corr;
      #pragma unroll
      for (int n = 0; n < 4; ++n) Oa[n][r] *= corr;
    }
    #pragma unroll
    for (int r = 0; r < 4; ++r) {
      #pragma unroll
      for (int off = 1; off < 16; off <<= 1)
        psum[r] += __shfl_xor(psum[r], off);
      l_run[r] += psum[r];
    }

    // ---- P -> LDS (D-frag layout -> row-major), then PV ----
    #pragma unroll
    for (int kb = 0; kb < 4; ++kb)
      #pragma unroll
      for (int r = 0; r < 4; ++r)
        Ps[wid][hi*4 + r][kb*16 + lo] = f2bf(sc[kb][r]);

    bf16x8 pa[2];
    #pragma unroll
    for (int kc = 0; kc < 2; ++kc)
      pa[kc] = *(const bf16x8*)&Ps[wid][lo][kc*32 + hi*8];
    #pragma unroll
    for (int n = 0; n < 4; ++n) {
      #pragma unroll
      for (int kc = 0; kc < 2; ++kc) {
        bf16x8 vf = *(const bf16x8*)&Vt[n*16 + lo][kc*32 + hi*8];
        Oa[n] = __builtin_amdgcn_mfma_f32_16x16x32_bf16(pa[kc], vf, Oa[n], 0, 0, 0);
      }
    }
  }

  // ---- epilogue: O / l, write bf16 ----
  #pragma unroll
  for (int r = 0; r < 4; ++r) {
    const float inv = 1.f / l_run[r];
    const int qq = q0 + hi*4 + r;
    bf16* Op = attn + ((size_t)qq * DB + t) * EE + h * HDIM;
    #pragma unroll
    for (int n = 0; n < 4; ++n)
      Op[n*16 + lo] = f2bf(Oa[n][r] * inv);
  }
}

// ---------------------------------------------------------------------------
// Col attention (unchanged): one block per (n, b, h), S=32, no mask.
// ---------------------------------------------------------------------------
__global__ __launch_bounds__(256) void attn_col_kernel(
    const bf16* __restrict__ qkv, bf16* __restrict__ attn)
{
  int bid = blockIdx.x;
  int n = bid >> 4;
  int b = (bid >> 2) & 3;
  int h = bid & 3;
  int tid = threadIdx.x;

  __shared__ float Qs[DD][HDIM], Ks[DD][HDIM], Vs[DD][HDIM];
  __shared__ float P[DD][DD+1];

  for (int i = tid; i < DD*HDIM; i += 256) {
    int dq = i >> 6, e = i & 63;
    size_t base = (((size_t)dq*NN + n)*BB + b)*QKV3 + h*HDIM + e;
    Qs[dq][e] = bf2f(qkv[base]);
    Ks[dq][e] = bf2f(qkv[base + EE]);
    Vs[dq][e] = bf2f(qkv[base + 2*EE]);
  }
  __syncthreads();

  for (int i = tid; i < DD*DD; i += 256) {
    int qi = i >> 5, ki = i & 31;
    float s = 0.f;
    #pragma unroll
    for (int e = 0; e < HDIM; ++e) s += Qs[qi][e]*Ks[ki][e];
    P[qi][ki] = s * 0.125f;
  }
  __syncthreads();

  if (tid < DD) {
    float mx = -1e30f;
    for (int ki = 0; ki < DD; ++ki) mx = fmaxf(mx, P[tid][ki]);
    float sum = 0.f;
    for (int ki = 0; ki < DD; ++ki) {
      float p = __expf(P[tid][ki] - mx);
      P[tid][ki] = p;
      sum += p;
    }
    float invs = 1.f / sum;
    for (int ki = 0; ki < DD; ++ki) P[tid][ki] *= invs;
  }
  __syncthreads();

  for (int i = tid; i < DD*HDIM; i += 256) {
    int qi = i >> 6, e = i & 63;
    float acc = 0.f;
    #pragma unroll
    for (int ki = 0; ki < DD; ++ki) acc += P[qi][ki]*Vs[ki][e];
    attn[(((size_t)qi*NN + n)*BB + b)*EE + h*HDIM + e] = f2bf(acc);
  }
}

// ---------------------------------------------------------------------------
// Final: out = LayerNorm(src + acc).  One block per token.
// ---------------------------------------------------------------------------
__global__ __launch_bounds__(256) void ln_kernel(
    const float* __restrict__ src, const float* __restrict__ acc,
    const float* __restrict__ g, const float* __restrict__ b,
    float* __restrict__ out)
{
  int m = blockIdx.x;
  int e = threadIdx.x;
  __shared__ float red[256];
  size_t idx = (size_t)m*EE + e;
  float x = src[idx] + acc[idx];
  red[e] = x;
  __syncthreads();
  for (int s2 = 128; s2 > 0; s2 >>= 1) {
    if (e < s2) red[e] += red[e+s2];
    __syncthreads();
  }
  float mu = red[0] * (1.f/EE);
  __syncthreads();
  float xm = x - mu;
  red[e] = xm*xm;
  __syncthreads();
  for (int s2 = 128; s2 > 0; s2 >>= 1) {
    if (e < s2) red[e] += red[e+s2];
    __syncthreads();
  }
  float var = red[0] * (1.f/EE);
  out[idx] = xm * rsqrtf(var + 1e-5f) * g[e] + b[e];
}

// ---------------------------------------------------------------------------
extern "C" void kernel_launch(void* const* d_in, const int* in_sizes, int n_in,
                              void* d_out, int out_size, void* d_ws, size_t ws_size,
                              hipStream_t stream)
{
  const float* src      = (const float*)d_in[0];
  const float* w_in_row = (const float*)d_in[1];
  const float* b_in_row = (const float*)d_in[2];
  const float* w_out_row= (const float*)d_in[3];
  const float* b_out_row= (const float*)d_in[4];
  const float* w_in_col = (const float*)d_in[5];
  const float* b_in_col = (const float*)d_in[6];
  const float* w_out_col= (const float*)d_in[7];
  const float* b_out_col= (const float*)d_in[8];
  const float* ln_g     = (const float*)d_in[9];
  const float* ln_b     = (const float*)d_in[10];
  const int*   sep_ptr  = (const int*)d_in[12];
  float* out = (float*)d_out;

  char* ws = (char*)d_ws;
  bf16*  qkv  = (bf16*)(ws);
  bf16*  attn = (bf16*)(ws + 100663296);
  float* acc  = (float*)(ws + 134217728);

  dim3 blk(256);

  // 1. row QKV
  gemm_kernel<0,0><<<dim3(QKV3/64, MTOK/64), blk, 0, stream>>>(
      src, w_in_row, b_in_row, qkv, QKV3);
  // 2. row attention (MFMA flash)
  attn_row_mfma<<<dim3(DB*HH*8), blk, 0, stream>>>(qkv, attn, sep_ptr);
  // 3. row out-proj -> acc (SET)
  gemm_kernel<2,1><<<dim3(EE/64, MTOK/64), blk, 0, stream>>>(
      attn, w_out_row, b_out_row, acc, EE);
  // 4. col QKV (A permuted to col-token order)
  gemm_kernel<1,0><<<dim3(QKV3/64, MTOK/64), blk, 0, stream>>>(
      src, w_in_col, b_in_col, qkv, QKV3);
  // 5. col attention
  attn_col_kernel<<<dim3(NN*BB*HH), blk, 0, stream>>>(qkv, attn);
  // 6. col out-proj -> acc (ADD, permuted)
  gemm_kernel<2,2><<<dim3(EE/64, MTOK/64), blk, 0, stream>>>(
      attn, w_out_col, b_out_col, acc, EE);
  // 7. residual + LayerNorm
  ln_kernel<<<dim3(MTOK), blk, 0, stream>>>(src, acc, ln_g, ln_b, out);
}

// Round 3
// 532.547 us; speedup vs baseline: 15.0174x; 3.1822x over previous
//
#include <hip/hip_runtime.h>
#include <hip/hip_bf16.h>
#include <cstdint>
#include <cstddef>

// AxialAttentionModule round 3: projection GEMMs moved to MFMA (m97-style
// 128x128 tile, global_load_lds w=16, XOR-swizzled LDS via pre-swizzled
// global source). Row attn already MFMA flash. fp32->bf16 convert pass added.
//
// Fixed shapes: N=512 D=32 B=4 E=256 H=4 HD=64.  K=256 for all GEMMs.

typedef __hip_bfloat16 bf16;
typedef __attribute__((ext_vector_type(8))) short bf16x8;
typedef __attribute__((ext_vector_type(8))) short short8;
typedef __attribute__((ext_vector_type(4))) float f32x4;

#define NN 512
#define DD 32
#define BB 4
#define EE 256
#define HH 4
#define HDIM 64
#define DB (DD*BB)        // 128
#define MTOK (NN*DD*BB)   // 65536
#define QKV3 (3*EE)       // 768
#define QBLK 64
#define KBLK 64

__device__ __forceinline__ float bf2f(bf16 x){ return __bfloat162float(x); }
__device__ __forceinline__ bf16 f2bf(float x){ return __float2bfloat16(x); }

#define AS1C(p) ((const __attribute__((address_space(1))) void*)(p))
#define AS3(p)  ((__attribute__((address_space(3))) void*)(p))

// ---------------------------------------------------------------------------
// fp32 -> bf16 bulk convert (8 elems/thread, 16B stores). n % 8 == 0.
// ---------------------------------------------------------------------------
__global__ __launch_bounds__(256) void cvt_kernel(
    const float* __restrict__ in, bf16* __restrict__ out, int n)
{
  int i = (blockIdx.x * 256 + threadIdx.x) * 8;
  if (i >= n) return;
  const float* p = in + i;
  short8 o;
  #pragma unroll
  for (int j = 0; j < 8; ++j)
    ((bf16*)&o)[j] = f2bf(p[j]);
  *(short8*)(out + i) = o;
}

// ---------------------------------------------------------------------------
// MFMA GEMM: C[M, NOUT] = A[M,256] @ W[NOUT,256]^T + bias
//   A, W bf16 row-major (K contiguous).  M=65536.
// AMODE: 0 = A rows direct; 1 = A rows are col-token indices -> permuted load
// CMODE: 0 = bf16 write direct; 1 = f32 SET; 2 = f32 ADD at row-token index
// 128x128 tile, BK=64, 256 thr (4 waves, each a 64x64 quadrant).
// LDS linear [128][64] bf16; swizzle: byte_col ^= (row&7)<<4, applied on the
// GLOBAL source during global_load_lds staging and on ds_read (involution).
// ---------------------------------------------------------------------------
template<int AMODE, int CMODE, int NOUT>
__global__ __launch_bounds__(256) void gemm_mfma(
    const bf16* __restrict__ A, const bf16* __restrict__ W,
    const float* __restrict__ bias, void* __restrict__ Cv)
{
  __shared__ bf16 As[128][64];
  __shared__ bf16 Bs[128][64];
  const int bm = blockIdx.y, bn = blockIdx.x;
  const int tid  = threadIdx.x;
  const int wid  = tid >> 6;
  const int lane = tid & 63;
  const int lo = lane & 15, hi = lane >> 4;
  const int wr = wid >> 1, wc = wid & 1;

  // staging: each wave stages 32 rows of As and Bs per K-step, 4 insts each,
  // 8 rows/inst; lane l -> row (l>>3), linear byte col (l&7)*16, source col
  // XOR-swizzled so ds_read can use swizzled addressing on linear LDS.
  const int srow = lane >> 3;                       // 0..7
  const int slin = (lane & 7) << 4;                 // linear byte col
  const int ssrc = slin ^ (srow << 4);              // swizzled source byte col

  f32x4 acc[4][4] = {};

  for (int k0 = 0; k0 < 256; k0 += 64) {
    __syncthreads();
    #pragma unroll
    for (int i = 0; i < 4; ++i) {
      const int r = wid * 32 + i * 8 + srow;
      // A tile row -> global row
      int m = bm * 128 + r;
      size_t grow;
      if (AMODE == 0) {
        grow = (size_t)m;
      } else {
        int d = m >> 11, n = (m >> 2) & 511, b = m & 3;
        grow = (size_t)n * DB + d * BB + b;
      }
      const char* gpA = (const char*)(A + grow * EE + k0) + ssrc;
      __builtin_amdgcn_global_load_lds(AS1C(gpA), AS3(&As[wid*32 + i*8][0]), 16, 0, 0);
      // B tile row -> W row
      const int wn = bn * 128 + r;
      const char* gpB = (const char*)(W + (size_t)wn * EE + k0) + ssrc;
      __builtin_amdgcn_global_load_lds(AS1C(gpB), AS3(&Bs[wid*32 + i*8][0]), 16, 0, 0);
    }
    __syncthreads();

    #pragma unroll
    for (int kc = 0; kc < 2; ++kc) {
      const int cc = kc * 64 + hi * 16;   // byte col of this frag chunk
      bf16x8 af[4], bfr[4];
      #pragma unroll
      for (int i = 0; i < 4; ++i) {
        const int ra = wr * 64 + i * 16 + lo;
        af[i]  = *(const bf16x8*)((const char*)&As[ra][0] + (cc ^ ((ra & 7) << 4)));
        const int rb = wc * 64 + i * 16 + lo;
        bfr[i] = *(const bf16x8*)((const char*)&Bs[rb][0] + (cc ^ ((rb & 7) << 4)));
      }
      #pragma unroll
      for (int mi = 0; mi < 4; ++mi)
        #pragma unroll
        for (int ni = 0; ni < 4; ++ni)
          acc[mi][ni] = __builtin_amdgcn_mfma_f32_16x16x32_bf16(
              af[mi], bfr[ni], acc[mi][ni], 0, 0, 0);
    }
  }

  // epilogue
  float bv[4];
  #pragma unroll
  for (int ni = 0; ni < 4; ++ni)
    bv[ni] = bias[bn * 128 + wc * 64 + ni * 16 + lo];

  #pragma unroll
  for (int mi = 0; mi < 4; ++mi) {
    #pragma unroll
    for (int r = 0; r < 4; ++r) {
      const int m = bm * 128 + wr * 64 + mi * 16 + hi * 4 + r;
      #pragma unroll
      for (int ni = 0; ni < 4; ++ni) {
        const int col = bn * 128 + wc * 64 + ni * 16 + lo;
        const float val = acc[mi][ni][r] + bv[ni];
        if (CMODE == 0) {
          ((bf16*)Cv)[(size_t)m * NOUT + col] = f2bf(val);
        } else if (CMODE == 1) {
          ((float*)Cv)[(size_t)m * NOUT + col] = val;
        } else {
          int d = m >> 11, n2 = (m >> 2) & 511, b = m & 3;
          ((float*)Cv)[((size_t)n2 * DB + d * BB + b) * EE + col] += val;
        }
      }
    }
  }
}

// ---------------------------------------------------------------------------
// Row attention, MFMA flash-style (unchanged from round 2).
// ---------------------------------------------------------------------------
__global__ __launch_bounds__(256) void attn_row_mfma(
    const bf16* __restrict__ qkv, bf16* __restrict__ attn,
    const int* __restrict__ sep_ptr)
{
  const int bid = blockIdx.x;
  const int qt = bid & 7;
  const int h  = (bid >> 3) & 3;
  const int t  = bid >> 5;
  const int sep = *sep_ptr;

  const int tid  = threadIdx.x;
  const int wid  = tid >> 6;
  const int lane = tid & 63;
  const int lo = lane & 15, hi = lane >> 4;

  __shared__ bf16 Ks[KBLK][HDIM + 8];
  __shared__ bf16 Vt[HDIM][KBLK + 8];
  __shared__ bf16 Ps[4][16][KBLK + 8];

  const int qb = qt * QBLK;
  const int q0 = qb + wid * 16;

  bf16x8 qf[2];
  {
    const bf16* Qp = qkv + ((size_t)(q0 + lo) * DB + t) * QKV3 + h * HDIM;
    qf[0] = *(const bf16x8*)(Qp + hi * 8);
    qf[1] = *(const bf16x8*)(Qp + 32 + hi * 8);
  }

  f32x4 Oa[4] = {{0,0,0,0},{0,0,0,0},{0,0,0,0},{0,0,0,0}};
  float m_run[4] = {-1e30f,-1e30f,-1e30f,-1e30f};
  float l_run[4] = {0.f,0.f,0.f,0.f};

  const int nkt = (qb >= sep) ? ((sep + KBLK - 1) >> 6) : (NN >> 6);

  for (int kt = 0; kt < nkt; ++kt) {
    const int k0 = kt * KBLK;
    __syncthreads();
    {
      const int r = tid >> 2;
      const int c = (tid & 3) * 16;
      const bf16* Kp = qkv + ((size_t)(k0 + r) * DB + t) * QKV3 + EE + h * HDIM + c;
      bf16x8 kv0 = ((const bf16x8*)Kp)[0];
      bf16x8 kv1 = ((const bf16x8*)Kp)[1];
      *(bf16x8*)&Ks[r][c]     = kv0;
      *(bf16x8*)&Ks[r][c + 8] = kv1;
      const bf16* Vp = Kp + EE;
      bf16x8 vv0 = ((const bf16x8*)Vp)[0];
      bf16x8 vv1 = ((const bf16x8*)Vp)[1];
      #pragma unroll
      for (int j = 0; j < 8; ++j) {
        Vt[c + j][r]     = ((const bf16*)&vv0)[j];
        Vt[c + 8 + j][r] = ((const bf16*)&vv1)[j];
      }
    }
    __syncthreads();

    f32x4 sc[4];
    #pragma unroll
    for (int kb = 0; kb < 4; ++kb) {
      f32x4 a = {0,0,0,0};
      #pragma unroll
      for (int kc = 0; kc < 2; ++kc) {
        bf16x8 kf = *(const bf16x8*)&Ks[kb*16 + lo][kc*32 + hi*8];
        a = __builtin_amdgcn_mfma_f32_16x16x32_bf16(qf[kc], kf, a, 0, 0, 0);
      }
      sc[kb] = a;
    }

    float tmax[4] = {-1e30f,-1e30f,-1e30f,-1e30f};
    #pragma unroll
    for (int kb = 0; kb < 4; ++kb) {
      const int kk = k0 + kb*16 + lo;
      #pragma unroll
      for (int r = 0; r < 4; ++r) {
        float sv = sc[kb][r] * 0.125f;
        const int qq = q0 + hi*4 + r;
        if (qq >= sep && kk >= sep) sv = -1e30f;
        sc[kb][r] = sv;
        tmax[r] = fmaxf(tmax[r], sv);
      }
    }
    #pragma unroll
    for (int r = 0; r < 4; ++r) {
      #pragma unroll
      for (int off = 1; off < 16; off <<= 1)
        tmax[r] = fmaxf(tmax[r], __shfl_xor(tmax[r], off));
    }
    float psum[4];
    #pragma unroll
    for (int r = 0; r < 4; ++r) {
      const float mn = fmaxf(m_run[r], tmax[r]);
      const float corr = __expf(m_run[r] - mn);
      m_run[r] = mn;
      float s0 = 0.f;
      #pragma unroll
      for (int kb = 0; kb < 4; ++kb) {
        const float p = __expf(sc[kb][r] - mn);
        sc[kb][r] = p;
        s0 += p;
      }
      psum[r] = s0;
      l_run[r] *= corr;
      #pragma unroll
      for (int n = 0; n < 4; ++n) Oa[n][r] *= corr;
    }
    #pragma unroll
    for (int r = 0; r < 4; ++r) {
      #pragma unroll
      for (int off = 1; off < 16; off <<= 1)
        psum[r] += __shfl_xor(psum[r], off);
      l_run[r] += psum[r];
    }

    #pragma unroll
    for (int kb = 0; kb < 4; ++kb)
      #pragma unroll
      for (int r = 0; r < 4; ++r)
        Ps[wid][hi*4 + r][kb*16 + lo] = f2bf(sc[kb][r]);

    bf16x8 pa[2];
    #pragma unroll
    for (int kc = 0; kc < 2; ++kc)
      pa[kc] = *(const bf16x8*)&Ps[wid][lo][kc*32 + hi*8];
    #pragma unroll
    for (int n = 0; n < 4; ++n) {
      #pragma unroll
      for (int kc = 0; kc < 2; ++kc) {
        bf16x8 vf = *(const bf16x8*)&Vt[n*16 + lo][kc*32 + hi*8];
        Oa[n] = __builtin_amdgcn_mfma_f32_16x16x32_bf16(pa[kc], vf, Oa[n], 0, 0, 0);
      }
    }
  }

  #pragma unroll
  for (int r = 0; r < 4; ++r) {
    const float inv = 1.f / l_run[r];
    const int qq = q0 + hi*4 + r;
    bf16* Op = attn + ((size_t)qq * DB + t) * EE + h * HDIM;
    #pragma unroll
    for (int n = 0; n < 4; ++n)
      Op[n*16 + lo] = f2bf(Oa[n][r] * inv);
  }
}

// ---------------------------------------------------------------------------
// Col attention (unchanged): one block per (n, b, h), S=32, no mask.
// ---------------------------------------------------------------------------
__global__ __launch_bounds__(256) void attn_col_kernel(
    const bf16* __restrict__ qkv, bf16* __restrict__ attn)
{
  int bid = blockIdx.x;
  int n = bid >> 4;
  int b = (bid >> 2) & 3;
  int h = bid & 3;
  int tid = threadIdx.x;

  __shared__ float Qs[DD][HDIM], Ks[DD][HDIM], Vs[DD][HDIM];
  __shared__ float P[DD][DD+1];

  for (int i = tid; i < DD*HDIM; i += 256) {
    int dq = i >> 6, e = i & 63;
    size_t base = (((size_t)dq*NN + n)*BB + b)*QKV3 + h*HDIM + e;
    Qs[dq][e] = bf2f(qkv[base]);
    Ks[dq][e] = bf2f(qkv[base + EE]);
    Vs[dq][e] = bf2f(qkv[base + 2*EE]);
  }
  __syncthreads();

  for (int i = tid; i < DD*DD; i += 256) {
    int qi = i >> 5, ki = i & 31;
    float s = 0.f;
    #pragma unroll
    for (int e = 0; e < HDIM; ++e) s += Qs[qi][e]*Ks[ki][e];
    P[qi][ki] = s * 0.125f;
  }
  __syncthreads();

  if (tid < DD) {
    float mx = -1e30f;
    for (int ki = 0; ki < DD; ++ki) mx = fmaxf(mx, P[tid][ki]);
    float sum = 0.f;
    for (int ki = 0; ki < DD; ++ki) {
      float p = __expf(P[tid][ki] - mx);
      P[tid][ki] = p;
      sum += p;
    }
    float invs = 1.f / sum;
    for (int ki = 0; ki < DD; ++ki) P[tid][ki] *= invs;
  }
  __syncthreads();

  for (int i = tid; i < DD*HDIM; i += 256) {
    int qi = i >> 6, e = i & 63;
    float acc = 0.f;
    #pragma unroll
    for (int ki = 0; ki < DD; ++ki) acc += P[qi][ki]*Vs[ki][e];
    attn[(((size_t)qi*NN + n)*BB + b)*EE + h*HDIM + e] = f2bf(acc);
  }
}

// ---------------------------------------------------------------------------
// Final: out = LayerNorm(src + acc).  One block per token.
// ---------------------------------------------------------------------------
__global__ __launch_bounds__(256) void ln_kernel(
    const float* __restrict__ src, const float* __restrict__ acc,
    const float* __restrict__ g, const float* __restrict__ b,
    float* __restrict__ out)
{
  int m = blockIdx.x;
  int e = threadIdx.x;
  __shared__ float red[256];
  size_t idx = (size_t)m*EE + e;
  float x = src[idx] + acc[idx];
  red[e] = x;
  __syncthreads();
  for (int s2 = 128; s2 > 0; s2 >>= 1) {
    if (e < s2) red[e] += red[e+s2];
    __syncthreads();
  }
  float mu = red[0] * (1.f/EE);
  __syncthreads();
  float xm = x - mu;
  red[e] = xm*xm;
  __syncthreads();
  for (int s2 = 128; s2 > 0; s2 >>= 1) {
    if (e < s2) red[e] += red[e+s2];
    __syncthreads();
  }
  float var = red[0] * (1.f/EE);
  out[idx] = xm * rsqrtf(var + 1e-5f) * g[e] + b[e];
}

// ---------------------------------------------------------------------------
extern "C" void kernel_launch(void* const* d_in, const int* in_sizes, int n_in,
                              void* d_out, int out_size, void* d_ws, size_t ws_size,
                              hipStream_t stream)
{
  const float* src      = (const float*)d_in[0];
  const float* w_in_row = (const float*)d_in[1];
  const float* b_in_row = (const float*)d_in[2];
  const float* w_out_row= (const float*)d_in[3];
  const float* b_out_row= (const float*)d_in[4];
  const float* w_in_col = (const float*)d_in[5];
  const float* b_in_col = (const float*)d_in[6];
  const float* w_out_col= (const float*)d_in[7];
  const float* b_out_col= (const float*)d_in[8];
  const float* ln_g     = (const float*)d_in[9];
  const float* ln_b     = (const float*)d_in[10];
  const int*   sep_ptr  = (const int*)d_in[12];
  float* out = (float*)d_out;

  char* ws = (char*)d_ws;
  bf16*  qkv    = (bf16*)(ws);                       // 100663296 B
  bf16*  attn   = (bf16*)(ws + 100663296);           //  33554432 B
  float* acc    = (float*)(ws + 134217728);          //  67108864 B
  bf16*  src_bf = (bf16*)(ws + 201326592);           //  33554432 B
  bf16*  wbf_ir = (bf16*)(ws + 234881024);           //    393216 B
  bf16*  wbf_or = (bf16*)(ws + 235274240);           //    131072 B
  bf16*  wbf_ic = (bf16*)(ws + 235405312);           //    393216 B
  bf16*  wbf_oc = (bf16*)(ws + 235798528);           //    131072 B

  dim3 blk(256);

  // 0. converts
  cvt_kernel<<<dim3(MTOK*EE/8/256), blk, 0, stream>>>(src, src_bf, MTOK*EE);
  cvt_kernel<<<dim3(QKV3*EE/8/256), blk, 0, stream>>>(w_in_row, wbf_ir, QKV3*EE);
  cvt_kernel<<<dim3(EE*EE/8/256),   blk, 0, stream>>>(w_out_row, wbf_or, EE*EE);
  cvt_kernel<<<dim3(QKV3*EE/8/256), blk, 0, stream>>>(w_in_col, wbf_ic, QKV3*EE);
  cvt_kernel<<<dim3(EE*EE/8/256),   blk, 0, stream>>>(w_out_col, wbf_oc, EE*EE);

  // 1. row QKV (MFMA)
  gemm_mfma<0,0,QKV3><<<dim3(QKV3/128, MTOK/128), blk, 0, stream>>>(
      src_bf, wbf_ir, b_in_row, qkv);
  // 2. row attention (MFMA flash)
  attn_row_mfma<<<dim3(DB*HH*8), blk, 0, stream>>>(qkv, attn, sep_ptr);
  // 3. row out-proj -> acc SET (MFMA)
  gemm_mfma<0,1,EE><<<dim3(EE/128, MTOK/128), blk, 0, stream>>>(
      attn, wbf_or, b_out_row, acc);
  // 4. col QKV (MFMA, A rows permuted from row-token src_bf)
  gemm_mfma<1,0,QKV3><<<dim3(QKV3/128, MTOK/128), blk, 0, stream>>>(
      src_bf, wbf_ic, b_in_col, qkv);
  // 5. col attention
  attn_col_kernel<<<dim3(NN*BB*HH), blk, 0, stream>>>(qkv, attn);
  // 6. col out-proj -> acc ADD at row-token index (MFMA)
  gemm_mfma<0,2,EE><<<dim3(EE/128, MTOK/128), blk, 0, stream>>>(
      attn, wbf_oc, b_out_col, acc);
  // 7. residual + LayerNorm
  ln_kernel<<<dim3(MTOK), blk, 0, stream>>>(src, acc, ln_g, ln_b, out);
}

// Round 4
// 399.470 us; speedup vs baseline: 20.0202x; 1.3331x over previous
//
#include <hip/hip_runtime.h>
#include <hip/hip_bf16.h>
#include <cstdint>
#include <cstddef>

// AxialAttentionModule round 4:
//  - attn_row: QBLK=128, XCD-grouped (t,h), double-buffered reg-staged K/V,
//    conflict-free V^T staging.
//  - gemms: 1-D grid with per-XCD m-tile chunking (A L2 reuse); all layouts
//    row-token direct (col path permutes in attn_col instead).
//  - attn_col: vectorized loads, 8-lane parallel softmax.
//  - ln: float4 + wave shuffle reduce, 4 tokens/block.
// Fixed shapes: N=512 D=32 B=4 E=256 H=4 HD=64.

typedef __hip_bfloat16 bf16;
typedef __attribute__((ext_vector_type(8))) short bf16x8;
typedef __attribute__((ext_vector_type(8))) short short8;
typedef __attribute__((ext_vector_type(4))) float f32x4;

#define NN 512
#define DD 32
#define BB 4
#define EE 256
#define HH 4
#define HDIM 64
#define DB (DD*BB)        // 128
#define MTOK (NN*DD*BB)   // 65536
#define QKV3 (3*EE)       // 768
#define KBLK 64

__device__ __forceinline__ float bf2f(bf16 x){ return __bfloat162float(x); }
__device__ __forceinline__ bf16 f2bf(float x){ return __float2bfloat16(x); }

#define AS1C(p) ((const __attribute__((address_space(1))) void*)(p))
#define AS3(p)  ((__attribute__((address_space(3))) void*)(p))

// ---------------------------------------------------------------------------
// fp32 -> bf16 bulk convert
// ---------------------------------------------------------------------------
__global__ __launch_bounds__(256) void cvt_kernel(
    const float* __restrict__ in, bf16* __restrict__ out, int n)
{
  int i = (blockIdx.x * 256 + threadIdx.x) * 8;
  if (i >= n) return;
  const float* p = in + i;
  short8 o;
  #pragma unroll
  for (int j = 0; j < 8; ++j)
    ((bf16*)&o)[j] = f2bf(p[j]);
  *(short8*)(out + i) = o;
}

// ---------------------------------------------------------------------------
// MFMA GEMM: C[M, NOUT] = A[M,256] @ W[NOUT,256]^T + bias,  M = 65536.
// CMODE: 0 = bf16 SET; 1 = f32 SET; 2 = f32 ADD.   NT = NOUT/128 tiles.
// 1-D grid 512*NT; per-XCD chunking: xcd=bid&7 owns 64 contiguous m-tiles,
// n-tiles innermost -> A-panel (4 MB) resident in that XCD's L2.
// ---------------------------------------------------------------------------
template<int CMODE, int NT, int NOUT>
__global__ __launch_bounds__(256,2) void gemm_mfma(
    const bf16* __restrict__ A, const bf16* __restrict__ W,
    const float* __restrict__ bias, void* __restrict__ Cv)
{
  __shared__ bf16 As[128][64];
  __shared__ bf16 Bs[128][64];
  const int bid = blockIdx.x;
  const int xcd = bid & 7;
  const int i0  = bid >> 3;
  const int bm  = xcd * 64 + i0 / NT;
  const int bn  = i0 % NT;

  const int tid  = threadIdx.x;
  const int wid  = tid >> 6;
  const int lane = tid & 63;
  const int lo = lane & 15, hi = lane >> 4;
  const int wr = wid >> 1, wc = wid & 1;

  const int srow = lane >> 3;
  const int slin = (lane & 7) << 4;
  const int ssrc = slin ^ (srow << 4);

  f32x4 acc[4][4] = {};

  for (int k0 = 0; k0 < 256; k0 += 64) {
    __syncthreads();
    #pragma unroll
    for (int i = 0; i < 4; ++i) {
      const int r = wid * 32 + i * 8 + srow;
      const int m = bm * 128 + r;
      const char* gpA = (const char*)(A + (size_t)m * EE + k0) + ssrc;
      __builtin_amdgcn_global_load_lds(AS1C(gpA), AS3(&As[wid*32 + i*8][0]), 16, 0, 0);
      const int wn = bn * 128 + r;
      const char* gpB = (const char*)(W + (size_t)wn * EE + k0) + ssrc;
      __builtin_amdgcn_global_load_lds(AS1C(gpB), AS3(&Bs[wid*32 + i*8][0]), 16, 0, 0);
    }
    __syncthreads();

    #pragma unroll
    for (int kc = 0; kc < 2; ++kc) {
      const int cc = kc * 64 + hi * 16;
      bf16x8 af[4], bfr[4];
      #pragma unroll
      for (int i = 0; i < 4; ++i) {
        const int ra = wr * 64 + i * 16 + lo;
        af[i]  = *(const bf16x8*)((const char*)&As[ra][0] + (cc ^ ((ra & 7) << 4)));
        const int rb = wc * 64 + i * 16 + lo;
        bfr[i] = *(const bf16x8*)((const char*)&Bs[rb][0] + (cc ^ ((rb & 7) << 4)));
      }
      #pragma unroll
      for (int mi = 0; mi < 4; ++mi)
        #pragma unroll
        for (int ni = 0; ni < 4; ++ni)
          acc[mi][ni] = __builtin_amdgcn_mfma_f32_16x16x32_bf16(
              af[mi], bfr[ni], acc[mi][ni], 0, 0, 0);
    }
  }

  float bv[4];
  #pragma unroll
  for (int ni = 0; ni < 4; ++ni)
    bv[ni] = bias[bn * 128 + wc * 64 + ni * 16 + lo];

  #pragma unroll
  for (int mi = 0; mi < 4; ++mi) {
    #pragma unroll
    for (int r = 0; r < 4; ++r) {
      const int m = bm * 128 + wr * 64 + mi * 16 + hi * 4 + r;
      #pragma unroll
      for (int ni = 0; ni < 4; ++ni) {
        const int col = bn * 128 + wc * 64 + ni * 16 + lo;
        const float val = acc[mi][ni][r] + bv[ni];
        if (CMODE == 0) {
          ((bf16*)Cv)[(size_t)m * NOUT + col] = f2bf(val);
        } else if (CMODE == 1) {
          ((float*)Cv)[(size_t)m * NOUT + col] = val;
        } else {
          ((float*)Cv)[(size_t)m * NOUT + col] += val;
        }
      }
    }
  }
}

// ---------------------------------------------------------------------------
// Row attention, MFMA flash, QBLK=128.
// Grid 2048: xcd=bid&7, idx=bid>>3; pair=(t,h)=xcd*64+(idx>>2); qt=idx&3.
// 4 waves; wave owns 32 q rows (2 x 16-row frags). K-tiles of 64, double-
// buffered LDS, reg-staged with async overlap.
// ---------------------------------------------------------------------------
__global__ __launch_bounds__(256,2) void attn_row_mfma(
    const bf16* __restrict__ qkv, bf16* __restrict__ attn,
    const int* __restrict__ sep_ptr)
{
  const int bid = blockIdx.x;
  const int xcd = bid & 7;
  const int idx = bid >> 3;
  const int pair = xcd * 64 + (idx >> 2);
  const int qt = idx & 3;
  const int t = pair >> 2;
  const int h = pair & 3;
  const int sep = *sep_ptr;

  const int tid  = threadIdx.x;
  const int wid  = tid >> 6;
  const int lane = tid & 63;
  const int lo = lane & 15, hi = lane >> 4;

  __shared__ bf16 Ks[2][KBLK][72];
  __shared__ bf16 Vt[2][HDIM][72];
  __shared__ bf16 Ps[4][32][72];

  const int qb = qt * 128;
  const int q0 = qb + wid * 32;

  // Q fragments: 2 row-frags x 2 k-chunks
  bf16x8 qf[2][2];
  #pragma unroll
  for (int mf = 0; mf < 2; ++mf) {
    const bf16* Qp = qkv + ((size_t)(q0 + mf*16 + lo) * DB + t) * QKV3 + h * HDIM;
    qf[mf][0] = *(const bf16x8*)(Qp + hi * 8);
    qf[mf][1] = *(const bf16x8*)(Qp + 32 + hi * 8);
  }

  // staging thread assignments
  const int kr  = tid >> 2;            // K: row 0..63
  const int kc4 = (tid & 3) * 16;      // K: col base
  const int vr  = tid & 63;            // V: row 0..63 (lane)
  const int vc  = (tid >> 6) * 16;     // V: d-col base (wave-constant)
  const bf16* Kbase = qkv + ((size_t)kr * DB + t) * QKV3 + EE + h * HDIM + kc4;
  const bf16* Vbase = qkv + ((size_t)vr * DB + t) * QKV3 + 2*EE + h * HDIM + vc;
  const size_t kstep = (size_t)KBLK * DB * QKV3;

  f32x4 Oa[2][4] = {};
  float m_run[2][4], l_run[2][4];
  #pragma unroll
  for (int mf = 0; mf < 2; ++mf)
    #pragma unroll
    for (int r = 0; r < 4; ++r) { m_run[mf][r] = -1e30f; l_run[mf][r] = 0.f; }

  const int nkt = (qb >= sep) ? ((sep + KBLK - 1) >> 6) : (NN >> 6);

  // prologue: load tile 0 into regs
  bf16x8 kg0 = *(const bf16x8*)(Kbase);
  bf16x8 kg1 = *(const bf16x8*)(Kbase + 8);
  bf16x8 vg0 = *(const bf16x8*)(Vbase);
  bf16x8 vg1 = *(const bf16x8*)(Vbase + 8);

  for (int kt = 0; kt < nkt; ++kt) {
    const int k0 = kt * KBLK;
    const int p = kt & 1;

    // ---- regs -> LDS ----
    *(bf16x8*)&Ks[p][kr][kc4]     = kg0;
    *(bf16x8*)&Ks[p][kr][kc4 + 8] = kg1;
    #pragma unroll
    for (int j = 0; j < 8; ++j) {
      Vt[p][vc + j][vr]     = ((const bf16*)&vg0)[j];
      Vt[p][vc + 8 + j][vr] = ((const bf16*)&vg1)[j];
    }
    __syncthreads();

    // ---- issue next tile's loads (overlap with compute) ----
    if (kt + 1 < nkt) {
      const size_t off = (size_t)(kt + 1) * kstep;
      kg0 = *(const bf16x8*)(Kbase + off);
      kg1 = *(const bf16x8*)(Kbase + off + 8);
      vg0 = *(const bf16x8*)(Vbase + off);
      vg1 = *(const bf16x8*)(Vbase + off + 8);
    }

    // ---- QK^T ----
    f32x4 sc[2][4];
    #pragma unroll
    for (int kb = 0; kb < 4; ++kb) {
      sc[0][kb] = (f32x4){0,0,0,0};
      sc[1][kb] = (f32x4){0,0,0,0};
      #pragma unroll
      for (int kc = 0; kc < 2; ++kc) {
        bf16x8 kf = *(const bf16x8*)&Ks[p][kb*16 + lo][kc*32 + hi*8];
        sc[0][kb] = __builtin_amdgcn_mfma_f32_16x16x32_bf16(qf[0][kc], kf, sc[0][kb], 0, 0, 0);
        sc[1][kb] = __builtin_amdgcn_mfma_f32_16x16x32_bf16(qf[1][kc], kf, sc[1][kb], 0, 0, 0);
      }
    }

    // ---- scale + mask + online softmax ----
    #pragma unroll
    for (int mf = 0; mf < 2; ++mf) {
      float tmax[4] = {-1e30f,-1e30f,-1e30f,-1e30f};
      #pragma unroll
      for (int kb = 0; kb < 4; ++kb) {
        const int kk = k0 + kb*16 + lo;
        #pragma unroll
        for (int r = 0; r < 4; ++r) {
          float sv = sc[mf][kb][r] * 0.125f;
          const int qq = q0 + mf*16 + hi*4 + r;
          if (qq >= sep && kk >= sep) sv = -1e30f;
          sc[mf][kb][r] = sv;
          tmax[r] = fmaxf(tmax[r], sv);
        }
      }
      #pragma unroll
      for (int r = 0; r < 4; ++r) {
        #pragma unroll
        for (int off = 1; off < 16; off <<= 1)
          tmax[r] = fmaxf(tmax[r], __shfl_xor(tmax[r], off));
      }
      float psum[4];
      #pragma unroll
      for (int r = 0; r < 4; ++r) {
        const float mn = fmaxf(m_run[mf][r], tmax[r]);
        const float corr = __expf(m_run[mf][r] - mn);
        m_run[mf][r] = mn;
        float s0 = 0.f;
        #pragma unroll
        for (int kb = 0; kb < 4; ++kb) {
          const float pv = __expf(sc[mf][kb][r] - mn);
          sc[mf][kb][r] = pv;
          s0 += pv;
        }
        psum[r] = s0;
        l_run[mf][r] *= corr;
        #pragma unroll
        for (int n = 0; n < 4; ++n) Oa[mf][n][r] *= corr;
      }
      #pragma unroll
      for (int r = 0; r < 4; ++r) {
        #pragma unroll
        for (int off = 1; off < 16; off <<= 1)
          psum[r] += __shfl_xor(psum[r], off);
        l_run[mf][r] += psum[r];
      }
      // P -> LDS (per-wave slice)
      #pragma unroll
      for (int kb = 0; kb < 4; ++kb)
        #pragma unroll
        for (int r = 0; r < 4; ++r)
          Ps[wid][mf*16 + hi*4 + r][kb*16 + lo] = f2bf(sc[mf][kb][r]);
    }

    // ---- PV ----
    bf16x8 pa[2][2];
    #pragma unroll
    for (int mf = 0; mf < 2; ++mf)
      #pragma unroll
      for (int kc = 0; kc < 2; ++kc)
        pa[mf][kc] = *(const bf16x8*)&Ps[wid][mf*16 + lo][kc*32 + hi*8];
    #pragma unroll
    for (int n = 0; n < 4; ++n) {
      #pragma unroll
      for (int kc = 0; kc < 2; ++kc) {
        bf16x8 vf = *(const bf16x8*)&Vt[p][n*16 + lo][kc*32 + hi*8];
        Oa[0][n] = __builtin_amdgcn_mfma_f32_16x16x32_bf16(pa[0][kc], vf, Oa[0][n], 0, 0, 0);
        Oa[1][n] = __builtin_amdgcn_mfma_f32_16x16x32_bf16(pa[1][kc], vf, Oa[1][n], 0, 0, 0);
      }
    }
  }

  // ---- epilogue ----
  #pragma unroll
  for (int mf = 0; mf < 2; ++mf) {
    #pragma unroll
    for (int r = 0; r < 4; ++r) {
      const float inv = 1.f / l_run[mf][r];
      const int qq = q0 + mf*16 + hi*4 + r;
      bf16* Op = attn + ((size_t)qq * DB + t) * EE + h * HDIM;
      #pragma unroll
      for (int n = 0; n < 4; ++n)
        Op[n*16 + lo] = f2bf(Oa[mf][n][r] * inv);
    }
  }
}

// ---------------------------------------------------------------------------
// Col attention: block per (n,b,h); S=32 over D axis, no mask.
// qkv in ROW-TOKEN order: token (n,d,b) at row n*DB + d*BB + b.
// Vectorized staging, 8-lane-parallel softmax.
// ---------------------------------------------------------------------------
__global__ __launch_bounds__(256) void attn_col_kernel(
    const bf16* __restrict__ qkv, bf16* __restrict__ attn)
{
  const int bid = blockIdx.x;          // (n*4 + b)*4 + h
  const int n = bid >> 4;
  const int b = (bid >> 2) & 3;
  const int h = bid & 3;
  const int tid = threadIdx.x;

  __shared__ float Qs[DD*65], Kx[DD*65], Vs[DD*65];
  __shared__ float P[DD*33];

  // stage: thread -> (d = tid>>3, 8 cols at (tid&7)*8)
  {
    const int d = tid >> 3, c = (tid & 7) * 8;
    const size_t base = ((size_t)(n*DB + d*BB + b)) * QKV3 + h*HDIM + c;
    bf16x8 qv = *(const bf16x8*)(qkv + base);
    bf16x8 kv = *(const bf16x8*)(qkv + base + EE);
    bf16x8 vv = *(const bf16x8*)(qkv + base + 2*EE);
    #pragma unroll
    for (int j = 0; j < 8; ++j) {
      Qs[d*65 + c + j] = bf2f(((const bf16*)&qv)[j]);
      Kx[d*65 + c + j] = bf2f(((const bf16*)&kv)[j]);
      Vs[d*65 + c + j] = bf2f(((const bf16*)&vv)[j]);
    }
  }
  __syncthreads();

  // scores: thread (qi = tid>>3, 4 keys at (tid&7)*4)
  const int qi = tid >> 3, kg = tid & 7;
  {
    float s[4] = {0.f, 0.f, 0.f, 0.f};
    for (int e = 0; e < HDIM; ++e) {
      const float qv = Qs[qi*65 + e];
      #pragma unroll
      for (int j = 0; j < 4; ++j)
        s[j] += qv * Kx[(kg*4 + j)*65 + e];
    }
    float mx = -1e30f;
    #pragma unroll
    for (int j = 0; j < 4; ++j) { s[j] *= 0.125f; mx = fmaxf(mx, s[j]); }
    #pragma unroll
    for (int off = 1; off < 8; off <<= 1)
      mx = fmaxf(mx, __shfl_xor(mx, off));
    float sum = 0.f;
    #pragma unroll
    for (int j = 0; j < 4; ++j) { s[j] = __expf(s[j] - mx); sum += s[j]; }
    #pragma unroll
    for (int off = 1; off < 8; off <<= 1)
      sum += __shfl_xor(sum, off);
    const float inv = 1.f / sum;
    #pragma unroll
    for (int j = 0; j < 4; ++j)
      P[qi*33 + kg*4 + j] = s[j] * inv;
  }
  __syncthreads();

  // PV: thread (qi, 8 d-cols at (tid&7)*8)
  {
    const int eb = (tid & 7) * 8;
    float acc[8] = {};
    for (int ki = 0; ki < DD; ++ki) {
      const float pv = P[qi*33 + ki];
      #pragma unroll
      for (int j = 0; j < 8; ++j)
        acc[j] += pv * Vs[ki*65 + eb + j];
    }
    bf16x8 o;
    #pragma unroll
    for (int j = 0; j < 8; ++j)
      ((bf16*)&o)[j] = f2bf(acc[j]);
    *(bf16x8*)(attn + ((size_t)(n*DB + qi*BB + b)) * EE + h*HDIM + eb) = o;
  }
}

// ---------------------------------------------------------------------------
// Final: out = LayerNorm(src + acc).  4 tokens/block, float4, shuffle reduce.
// ---------------------------------------------------------------------------
__global__ __launch_bounds__(256) void ln_kernel(
    const float* __restrict__ src, const float* __restrict__ acc,
    const float* __restrict__ g, const float* __restrict__ b,
    float* __restrict__ out)
{
  const int m = blockIdx.x * 4 + (threadIdx.x >> 6);
  const int lane = threadIdx.x & 63;
  const float4 s4 = ((const float4*)src)[(size_t)m*64 + lane];
  const float4 a4 = ((const float4*)acc)[(size_t)m*64 + lane];
  float4 x;
  x.x = s4.x + a4.x; x.y = s4.y + a4.y; x.z = s4.z + a4.z; x.w = s4.w + a4.w;
  float sum = x.x + x.y + x.z + x.w;
  #pragma unroll
  for (int off = 1; off < 64; off <<= 1) sum += __shfl_xor(sum, off);
  const float mu = sum * (1.f/EE);
  float4 d;
  d.x = x.x - mu; d.y = x.y - mu; d.z = x.z - mu; d.w = x.w - mu;
  float ss = d.x*d.x + d.y*d.y + d.z*d.z + d.w*d.w;
  #pragma unroll
  for (int off = 1; off < 64; off <<= 1) ss += __shfl_xor(ss, off);
  const float rstd = rsqrtf(ss * (1.f/EE) + 1e-5f);
  const float4 g4 = ((const float4*)g)[lane];
  const float4 b4 = ((const float4*)b)[lane];
  float4 o;
  o.x = d.x * rstd * g4.x + b4.x;
  o.y = d.y * rstd * g4.y + b4.y;
  o.z = d.z * rstd * g4.z + b4.z;
  o.w = d.w * rstd * g4.w + b4.w;
  ((float4*)out)[(size_t)m*64 + lane] = o;
}

// ---------------------------------------------------------------------------
extern "C" void kernel_launch(void* const* d_in, const int* in_sizes, int n_in,
                              void* d_out, int out_size, void* d_ws, size_t ws_size,
                              hipStream_t stream)
{
  const float* src      = (const float*)d_in[0];
  const float* w_in_row = (const float*)d_in[1];
  const float* b_in_row = (const float*)d_in[2];
  const float* w_out_row= (const float*)d_in[3];
  const float* b_out_row= (const float*)d_in[4];
  const float* w_in_col = (const float*)d_in[5];
  const float* b_in_col = (const float*)d_in[6];
  const float* w_out_col= (const float*)d_in[7];
  const float* b_out_col= (const float*)d_in[8];
  const float* ln_g     = (const float*)d_in[9];
  const float* ln_b     = (const float*)d_in[10];
  const int*   sep_ptr  = (const int*)d_in[12];
  float* out = (float*)d_out;

  char* ws = (char*)d_ws;
  bf16*  qkv    = (bf16*)(ws);                       // 100663296 B
  bf16*  attn   = (bf16*)(ws + 100663296);           //  33554432 B
  float* acc    = (float*)(ws + 134217728);          //  67108864 B
  bf16*  src_bf = (bf16*)(ws + 201326592);           //  33554432 B
  bf16*  wbf_ir = (bf16*)(ws + 234881024);
  bf16*  wbf_or = (bf16*)(ws + 235274240);
  bf16*  wbf_ic = (bf16*)(ws + 235405312);
  bf16*  wbf_oc = (bf16*)(ws + 235798528);

  dim3 blk(256);

  // converts
  cvt_kernel<<<dim3(MTOK*EE/8/256), blk, 0, stream>>>(src, src_bf, MTOK*EE);
  cvt_kernel<<<dim3(QKV3*EE/8/256), blk, 0, stream>>>(w_in_row, wbf_ir, QKV3*EE);
  cvt_kernel<<<dim3(EE*EE/8/256),   blk, 0, stream>>>(w_out_row, wbf_or, EE*EE);
  cvt_kernel<<<dim3(QKV3*EE/8/256), blk, 0, stream>>>(w_in_col, wbf_ic, QKV3*EE);
  cvt_kernel<<<dim3(EE*EE/8/256),   blk, 0, stream>>>(w_out_col, wbf_oc, EE*EE);

  // row path
  gemm_mfma<0,6,QKV3><<<dim3(512*6), blk, 0, stream>>>(src_bf, wbf_ir, b_in_row, qkv);
  attn_row_mfma<<<dim3(2048), blk, 0, stream>>>(qkv, attn, sep_ptr);
  gemm_mfma<1,2,EE><<<dim3(512*2), blk, 0, stream>>>(attn, wbf_or, b_out_row, acc);

  // col path (row-token layout throughout)
  gemm_mfma<0,6,QKV3><<<dim3(512*6), blk, 0, stream>>>(src_bf, wbf_ic, b_in_col, qkv);
  attn_col_kernel<<<dim3(NN*BB*HH), blk, 0, stream>>>(qkv, attn);
  gemm_mfma<2,2,EE><<<dim3(512*2), blk, 0, stream>>>(attn, wbf_oc, b_out_col, acc);

  // residual + LayerNorm
  ln_kernel<<<dim3(MTOK/4), blk, 0, stream>>>(src, acc, ln_g, ln_b, out);
}